// Round 3
// baseline (801.512 us; speedup 1.0000x reference)
//
#include <hip/hip_runtime.h>
#include <hip/hip_bf16.h>
#include <math.h>

// Problem constants (B=2,S=2048,D=1024,H=4096,E=8,K=2)
#define NTOK 4096
#define DD   1024
#define HH   4096
#define EE   8
#define NSLOT 8192          // NTOK * K (every token picks exactly 2 experts)
#define NSLOT_PAD 8448      // +256 guard rows so a 256-row tile never reads OOB
#define RBLK 128            // router blocks (32 tokens each)

typedef __bf16 bf16x8 __attribute__((ext_vector_type(8)));
typedef float  f32x4  __attribute__((ext_vector_type(4)));
typedef unsigned short u16x8 __attribute__((ext_vector_type(8)));

// s_waitcnt imm encoding (gfx9 family): vmcnt[3:0]+[15:14], expcnt[6:4], lgkmcnt[11:8]
#define WAITCNT_VM(n) (((n) & 0xF) | (0x7 << 4) | (0xF << 8) | (((n) >> 4) << 14))

// ---------------- ws layout (bytes) ----------------
#define WS_COUNTS     0
#define WS_CURSORS    64
#define WS_OFFSETS    128
#define WS_IMP        256
#define WS_TOPK_IDX   512
#define WS_TOPK_GATE  33280
#define WS_SLOT_OF    66048
#define WS_TOKEN_LIST 98816
// xg bf16 [8448][1024]         = 17,301,504 B
#define WS_XG         131584
// hbuf bf16 [8448][4096]       = 69,206,016 B  (rows >= 8192 are guard rows)
#define WS_HBUF       17433088
// ybuf f32 [8192][1024]        = 33,554,432 B
#define WS_YBUF       86639104
// W1bt bf16 [8][4096][1024]    = 67,108,864 B
#define WS_W1BT       120193536
// W2bt bf16 [8][1024][4096]    = 67,108,864 B
#define WS_W2BT       187302400
// total                        = 254,411,264 B (~242.6 MiB)
// Router partials live in hbuf's guard-row region (never stored by gemm1,
// read only as masked garbage by gemm2):
#define WS_CNT_PART   (WS_HBUF + (size_t)NSLOT * HH * 2)          // int[128*8]
#define WS_IMP_PART   (WS_HBUF + (size_t)NSLOT * HH * 2 + 4096)   // float[128*8]

__device__ __forceinline__ float gelu_exact(float v) {
    return 0.5f * v * (1.0f + erff(v * 0.70710678118654752f));
}

__device__ __forceinline__ void async_copy16(const __bf16* g, __bf16* l) {
    __builtin_amdgcn_global_load_lds(
        (const __attribute__((address_space(1))) void*)g,
        (__attribute__((address_space(3))) void*)l, 16, 0, 0);
}

// ---------------- Router: 8 lanes per token, no global atomics ----------
__launch_bounds__(256)
__global__ void router_kernel(const float* __restrict__ x,
                              const float* __restrict__ Wr,
                              const float* __restrict__ br,
                              int* __restrict__ cntPart,
                              float* __restrict__ impPart,
                              int* __restrict__ topk_idx,
                              float* __restrict__ topk_gate) {
    __shared__ float WrL[DD * EE];      // 32 KB
    __shared__ float impW[4][EE];
    __shared__ int cntL[EE];
    int tid = threadIdx.x;
    int lane = tid & 63, wave = tid >> 6;
    int grp = lane >> 3, e = lane & 7;
    int t = blockIdx.x * 32 + wave * 8 + grp;

    for (int i = tid; i < DD * EE / 4; i += 256)
        ((float4*)WrL)[i] = ((const float4*)Wr)[i];
    if (tid < EE) cntL[tid] = 0;
    __syncthreads();

    const float* xr = x + (size_t)t * DD;
    float acc = 0.f;
#pragma unroll 4
    for (int d = 0; d < DD; d += 4) {
        float4 xv = *(const float4*)(xr + d);
        acc = fmaf(xv.x, WrL[(d + 0) * EE + e], acc);
        acc = fmaf(xv.y, WrL[(d + 1) * EE + e], acc);
        acc = fmaf(xv.z, WrL[(d + 2) * EE + e], acc);
        acc = fmaf(xv.w, WrL[(d + 3) * EE + e], acc);
    }
    float l = acc + br[e];

    // softmax prob for (t,e) across the 8 lanes of this token
    float m = l;
#pragma unroll
    for (int mk = 1; mk <= 4; mk <<= 1) m = fmaxf(m, __shfl_xor(m, mk, 64));
    float p = expf(l - m);
    float s = p;
#pragma unroll
    for (int mk = 1; mk <= 4; mk <<= 1) s += __shfl_xor(s, mk, 64);
    p /= s;

    // top-1 argmax (ties -> lowest index, matching jax.lax.top_k)
    float bl = l; int be = e;
#pragma unroll
    for (int mk = 1; mk <= 4; mk <<= 1) {
        float ol = __shfl_xor(bl, mk, 64);
        int   oe = __shfl_xor(be, mk, 64);
        if (ol > bl || (ol == bl && oe < be)) { bl = ol; be = oe; }
    }
    int e1 = be; float l1 = bl;
    // top-2
    float cl = (e == e1) ? -INFINITY : l; int ce = e;
#pragma unroll
    for (int mk = 1; mk <= 4; mk <<= 1) {
        float ol = __shfl_xor(cl, mk, 64);
        int   oe = __shfl_xor(ce, mk, 64);
        if (ol > cl || (ol == cl && oe < ce)) { cl = ol; ce = oe; }
    }
    int e2 = ce; float l2 = cl;

    if (e == 0) {
        float bb = expf(l2 - l1);        // <= 1
        float g1 = 1.f / (1.f + bb);
        topk_idx[t * 2 + 0] = e1; topk_idx[t * 2 + 1] = e2;
        topk_gate[t * 2 + 0] = g1; topk_gate[t * 2 + 1] = bb * g1;
        atomicAdd(&cntL[e1], 1);         // LDS atomics only
        atomicAdd(&cntL[e2], 1);
    }

    // importance: sum p over the 8 token-groups in this wave
#pragma unroll
    for (int mk = 8; mk <= 32; mk <<= 1) p += __shfl_xor(p, mk, 64);
    if (lane < 8) impW[wave][lane] = p;
    __syncthreads();
    if (tid < EE) {
        float v = impW[0][tid] + impW[1][tid] + impW[2][tid] + impW[3][tid];
        impPart[blockIdx.x * EE + tid] = v;
        cntPart[blockIdx.x * EE + tid] = cntL[tid];
    }
}

// ---------------- Prefix: sum partials -> offsets/cursors + aux loss -------
__launch_bounds__(64)
__global__ void prefix_kernel(const int* __restrict__ cntPart,
                              const float* __restrict__ impPart,
                              int* __restrict__ offsets,
                              int* __restrict__ cursors,
                              float* __restrict__ aux_out) {
    __shared__ int cs[EE];
    __shared__ float is[EE];
    int tid = threadIdx.x;
    if (tid < EE) {
        int c = 0; float v = 0.f;
        for (int b = 0; b < RBLK; b++) {
            c += cntPart[b * EE + tid];
            v += impPart[b * EE + tid];
        }
        cs[tid] = c; is[tid] = v;
    }
    __syncthreads();
    if (tid == 0) {
        int o = 0;
        for (int e = 0; e < EE; e++) { offsets[e] = o; cursors[e] = o; o += cs[e]; }
        offsets[EE] = o;
        float aux = 0.f;
        for (int e = 0; e < EE; e++) {
            float d = is[e] / (float)NTOK - 1.0f / (float)EE;
            aux += d * d;
        }
        aux_out[0] = aux / (float)EE;
    }
}

// ---------------- Scatter: two-phase, 8 global atomics per block -----------
__launch_bounds__(256)
__global__ void scatter_kernel(const int* __restrict__ topk_idx,
                               int* __restrict__ cursors,
                               int* __restrict__ token_list,
                               int* __restrict__ slot_of) {
    __shared__ int lcnt[EE];
    __shared__ int lbase[EE];
    int tid = threadIdx.x;
    int t = blockIdx.x * 256 + tid;
    if (tid < EE) lcnt[tid] = 0;
    __syncthreads();
    int e0 = topk_idx[t * 2 + 0], e1 = topk_idx[t * 2 + 1];
    int r0 = atomicAdd(&lcnt[e0], 1);
    int r1 = atomicAdd(&lcnt[e1], 1);
    __syncthreads();
    if (tid < EE) lbase[tid] = atomicAdd(&cursors[tid], lcnt[tid]);
    __syncthreads();
    int s0 = lbase[e0] + r0, s1 = lbase[e1] + r1;
    token_list[s0] = t; token_list[s1] = t;
    slot_of[t * 2 + 0] = s0; slot_of[t * 2 + 1] = s1;
}

// ---------------- Gather x rows into packed bf16 slot rows ----------------
__launch_bounds__(256)
__global__ void gather_x_kernel(const float* __restrict__ x,
                                const int* __restrict__ token_list,
                                __bf16* __restrict__ xg) {
    int s = blockIdx.x;
    int t = token_list[s];
    int tid = threadIdx.x;           // 256 threads x float4 = 1024 elems
    float4 v = ((const float4*)(x + (size_t)t * DD))[tid];
    __bf16 tmp[4] __attribute__((aligned(8)));
    tmp[0] = (__bf16)v.x; tmp[1] = (__bf16)v.y;
    tmp[2] = (__bf16)v.z; tmp[3] = (__bf16)v.w;
    ((ushort4*)(xg + (size_t)s * DD))[tid] = *(ushort4*)tmp;
}

// ---------------- Weight convert+transpose: [E][R][C] f32 -> [E][C][R] bf16 ----
__launch_bounds__(256)
__global__ void transpose_w_kernel(const float* __restrict__ in,
                                   __bf16* __restrict__ out,
                                   int R, int C) {
    int e = blockIdx.z;
    int c0 = blockIdx.x * 64, r0 = blockIdx.y * 64;
    __shared__ float tile[64][65];
    int tid = threadIdx.x;
    const float* ip = in + (size_t)e * R * C;
#pragma unroll
    for (int i = 0; i < 4; i++) {
        int flat = i * 256 + tid;
        int r = flat >> 4, c4 = (flat & 15) * 4;
        float4 v = *(const float4*)(ip + (size_t)(r0 + r) * C + c0 + c4);
        tile[r][c4 + 0] = v.x; tile[r][c4 + 1] = v.y;
        tile[r][c4 + 2] = v.z; tile[r][c4 + 3] = v.w;
    }
    __syncthreads();
    __bf16* op = out + (size_t)e * C * R;
    // write side: 16B per lane (ushort8), 2 passes
#pragma unroll
    for (int i = 0; i < 2; i++) {
        int flat = i * 256 + tid;
        int c = flat >> 3, r8 = (flat & 7) * 8;
        __bf16 tmp[8] __attribute__((aligned(16)));
#pragma unroll
        for (int j = 0; j < 8; j++) tmp[j] = (__bf16)tile[r8 + j][c];
        *(u16x8*)(op + (size_t)(c0 + c) * R + r0 + r8) = *(u16x8*)tmp;
    }
}

// ============ Grouped GEMM 1: 256x256 tile, BK=64, deep 4-phase ============
// C[m][n] = A[m][:] . Bt[n][:].  8 waves in 2M x 4N grid -> wave tile 128x64
// (43.7 FLOP per LDS byte read, 2x the 32x64 wave tile).  128 KB LDS,
// 1 block/CU; the counted-vmcnt phase pipeline self-hides stalls:
// per K-tile 4 phases, each = [vm-wait?] -> barrier -> stage 1 unit of tile
// t+1 -> frag ds_reads -> 16 MFMA (setprio-wrapped).  Stage-unit issue order
// (Ah0,Bh0,Bh1,Ah1) = consumption order; vm(2) at P1/P2 only (never 0
// mid-loop).  Staging after the barrier is safe: the previous phase's MFMAs
// lgkm-drained their ds_reads, so the barrier certifies all reads of the
// target buffer completed.  XOR chunk swizzle (proven 0-conflict): stage lane
// writes global col-chunk (lane&7)^(lane>>3); frag reads chunk slot^(row&7).
template <int N, int K, bool GELU, typename OutT>
__launch_bounds__(512, 2)
__global__ void gemm256_kernel(const __bf16* __restrict__ A,
                               const __bf16* __restrict__ Bt,
                               const float* __restrict__ bias,
                               const int* __restrict__ offsets,
                               OutT* __restrict__ Out) {
    constexpr int NT = K / 64;
    int e = blockIdx.z, ct = blockIdx.x, rt = blockIdx.y;
    int obase = offsets[e], cnt = offsets[e + 1] - obase;
    int m0 = rt * 256;
    if (m0 >= cnt) return;

    __shared__ __bf16 As[2][32 * 512];   // 256 rows x 64 K as 32 chunks
    __shared__ __bf16 Bs[2][32 * 512];

    int tid = threadIdx.x, lane = tid & 63, wave = tid >> 6;
    int quad = lane >> 4, m16 = lane & 15;
    int wm = wave & 1, wn = wave >> 1;        // 2M x 4N wave grid
    int srow = lane >> 3;
    int scol = ((lane & 7) ^ srow) * 8;

    const __bf16* Ag = A + (size_t)(obase + m0) * K + scol;
    const __bf16* Bg = Bt + ((size_t)e * N + (size_t)ct * 256) * K + scol;
    const __bf16* Arow = Ag + (size_t)(wave * 8 + srow) * K;   // per-lane base
    const __bf16* Brow = Bg + (size_t)(wave * 8 + srow) * K;

    f32x4 acc[8][4] = {};
    bf16x8 af[4], bfr[4];

#define STG_AH(buf, h, k0)                                                    \
    { async_copy16(Arow + (size_t)((h) * 128) * K + (k0),                     \
                   &As[buf][((h) * 16 + wave) * 512]);                        \
      async_copy16(Arow + (size_t)((h) * 128 + 64) * K + (k0),                \
                   &As[buf][((h) * 16 + 8 + wave) * 512]); }
#define STG_BH(buf, h, k0)                                                    \
    { async_copy16(Brow + (size_t)((h) * 128) * K + (k0),                     \
                   &Bs[buf][((h) * 16 + wave) * 512]);                        \
      async_copy16(Brow + (size_t)((h) * 128 + 64) * K + (k0),                \
                   &Bs[buf][((h) * 16 + 8 + wave) * 512]); }

#define READ_A(buf, mh, ks)                                                   \
    { _Pragma("unroll")                                                       \
      for (int mi = 0; mi < 4; mi++) {                                        \
          int r = (mh) * 128 + (mi * 2 + wm) * 16 + m16;                      \
          af[mi] = *(const bf16x8*)(&As[buf][(r >> 3) * 512 + (r & 7) * 64    \
                               + ((((ks) * 4 + quad) ^ (r & 7)) * 8)]); } }
#define READ_B(buf, ks)                                                       \
    { _Pragma("unroll")                                                       \
      for (int ni = 0; ni < 4; ni++) {                                        \
          int r = (ni * 4 + wn) * 16 + m16;                                   \
          bfr[ni] = *(const bf16x8*)(&Bs[buf][(r >> 3) * 512 + (r & 7) * 64   \
                               + ((((ks) * 4 + quad) ^ (r & 7)) * 8)]); } }

#define MMA(mh)                                                               \
    { __builtin_amdgcn_s_setprio(1);                                         \
      _Pragma("unroll")                                                       \
      for (int mi = 0; mi < 4; mi++)                                          \
          _Pragma("unroll")                                                   \
          for (int ni = 0; ni < 4; ni++)                                      \
              acc[(mh) * 4 + mi][ni] = __builtin_amdgcn_mfma_f32_16x16x32_bf16(\
                  af[mi], bfr[ni], acc[(mh) * 4 + mi][ni], 0, 0, 0);          \
      __builtin_amdgcn_s_setprio(0); }

    // prologue: tile 0, issue order = consumption order
    STG_AH(0, 0, 0); STG_BH(0, 0, 0); STG_BH(0, 1, 0); STG_AH(0, 1, 0);

    int cur = 0;
    for (int t = 0; t < NT - 1; t++) {
        int k1 = (t + 1) * 64, nxt = cur ^ 1;
        // P1 (mh0,ks0): needs Ah0,Bh0,Bh1 of t -> vm(2) leaves Ah1(t)
        __builtin_amdgcn_s_waitcnt(WAITCNT_VM(2));
        __builtin_amdgcn_s_barrier();
        STG_AH(nxt, 0, k1);
        READ_A(cur, 0, 0); READ_B(cur, 0);
        MMA(0);
        // P2 (mh1,ks0): needs Ah1(t) -> vm(2) leaves Ah0(t+1)
        __builtin_amdgcn_s_waitcnt(WAITCNT_VM(2));
        __builtin_amdgcn_s_barrier();
        STG_BH(nxt, 0, k1);
        READ_A(cur, 1, 0);
        MMA(1);
        // P3 (mh0,ks1): data already certified
        __builtin_amdgcn_s_barrier();
        STG_BH(nxt, 1, k1);
        READ_A(cur, 0, 1); READ_B(cur, 1);
        MMA(0);
        // P4 (mh1,ks1)
        __builtin_amdgcn_s_barrier();
        STG_AH(nxt, 1, k1);
        READ_A(cur, 1, 1);
        MMA(1);
        cur = nxt;
    }
    // final K-tile: draining waits, no prefetch
    __builtin_amdgcn_s_waitcnt(WAITCNT_VM(2));
    __builtin_amdgcn_s_barrier();
    READ_A(cur, 0, 0); READ_B(cur, 0);
    MMA(0);
    __builtin_amdgcn_s_waitcnt(WAITCNT_VM(0));
    READ_A(cur, 1, 0);
    MMA(1);
    READ_A(cur, 0, 1); READ_B(cur, 1);
    MMA(0);
    READ_A(cur, 1, 1);
    MMA(1);
#undef STG_AH
#undef STG_BH
#undef READ_A
#undef READ_B
#undef MMA

    // epilogue: +bias, optional gelu, masked store
    float bv[4];
#pragma unroll
    for (int ni = 0; ni < 4; ni++)
        bv[ni] = bias[(size_t)e * N + ct * 256 + (ni * 4 + wn) * 16 + m16];
#pragma unroll
    for (int mh = 0; mh < 2; mh++) {
#pragma unroll
        for (int mi = 0; mi < 4; mi++) {
#pragma unroll
            for (int rr = 0; rr < 4; rr++) {
                int row = mh * 128 + (mi * 2 + wm) * 16 + quad * 4 + rr;
                if (m0 + row < cnt) {
                    size_t orow = (size_t)(obase + m0 + row) * N + (size_t)ct * 256;
#pragma unroll
                    for (int ni = 0; ni < 4; ni++) {
                        float v = acc[mh * 4 + mi][ni][rr] + bv[ni];
                        if (GELU) v = gelu_exact(v);
                        Out[orow + (ni * 4 + wn) * 16 + m16] = (OutT)v;
                    }
                }
            }
        }
    }
}

// ============ Grouped GEMM 2: 128x128 tile, BK=64, 256 thr, 2/CU ==========
// 4 waves in 2M x 2N grid -> wave tile 64x64 (32.8 FLOP/B).  64 KB LDS ->
// 2 blocks/CU resident; 544 active blocks -> ~94% load balance on the
// N=1024 output shape.  Same 4-phase counted-vmcnt skeleton as gemm256
// (units A-h0,A-h1,B-h0,B-h1; vm(2) at P1/P2).
template <int N, int K, bool GELU, typename OutT>
__launch_bounds__(256, 2)
__global__ void gemm128d_kernel(const __bf16* __restrict__ A,
                                const __bf16* __restrict__ Bt,
                                const float* __restrict__ bias,
                                const int* __restrict__ offsets,
                                OutT* __restrict__ Out) {
    constexpr int NT = K / 64;
    int e = blockIdx.z, ct = blockIdx.x, rt = blockIdx.y;
    int obase = offsets[e], cnt = offsets[e + 1] - obase;
    int m0 = rt * 128;
    if (m0 >= cnt) return;

    __shared__ __bf16 As[2][16 * 512];   // 128 rows x 64 K as 16 chunks
    __shared__ __bf16 Bs[2][16 * 512];

    int tid = threadIdx.x, lane = tid & 63, wave = tid >> 6;   // 4 waves
    int quad = lane >> 4, m16 = lane & 15;
    int wm = wave & 1, wn = wave >> 1;        // 2M x 2N wave grid
    int srow = lane >> 3;
    int scol = ((lane & 7) ^ srow) * 8;

    const __bf16* Ag = A + (size_t)(obase + m0) * K + scol;
    const __bf16* Bg = Bt + ((size_t)e * N + (size_t)ct * 128) * K + scol;
    const __bf16* Arow = Ag + (size_t)(wave * 8 + srow) * K;
    const __bf16* Brow = Bg + (size_t)(wave * 8 + srow) * K;

    f32x4 acc[4][4] = {};
    bf16x8 af[4], bfr[2];

#define STG_AH(buf, h, k0)                                                    \
    { async_copy16(Arow + (size_t)((h) * 64) * K + (k0),                      \
                   &As[buf][((h) * 8 + wave) * 512]);                         \
      async_copy16(Arow + (size_t)((h) * 64 + 32) * K + (k0),                 \
                   &As[buf][((h) * 8 + 4 + wave) * 512]); }
#define STG_BH(buf, h, k0)                                                    \
    { async_copy16(Brow + (size_t)((h) * 64) * K + (k0),                      \
                   &Bs[buf][((h) * 8 + wave) * 512]);                         \
      async_copy16(Brow + (size_t)((h) * 64 + 32) * K + (k0),                 \
                   &Bs[buf][((h) * 8 + 4 + wave) * 512]); }

#define READ_A(buf, ks)                                                       \
    { _Pragma("unroll")                                                       \
      for (int mi = 0; mi < 4; mi++) {                                        \
          int r = (mi * 2 + wm) * 16 + m16;                                   \
          af[mi] = *(const bf16x8*)(&As[buf][(r >> 3) * 512 + (r & 7) * 64    \
                               + ((((ks) * 4 + quad) ^ (r & 7)) * 8)]); } }
#define READ_B2(buf, nh, ks)                                                  \
    { _Pragma("unroll")                                                       \
      for (int j = 0; j < 2; j++) {                                           \
          int r = (((nh) * 2 + j) * 2 + wn) * 16 + m16;                       \
          bfr[j] = *(const bf16x8*)(&Bs[buf][(r >> 3) * 512 + (r & 7) * 64    \
                               + ((((ks) * 4 + quad) ^ (r & 7)) * 8)]); } }

#define MMA2(nh)                                                              \
    { __builtin_amdgcn_s_setprio(1);                                         \
      _Pragma("unroll")                                                       \
      for (int mi = 0; mi < 4; mi++)                                          \
          _Pragma("unroll")                                                   \
          for (int j = 0; j < 2; j++)                                         \
              acc[mi][(nh) * 2 + j] = __builtin_amdgcn_mfma_f32_16x16x32_bf16(\
                  af[mi], bfr[j], acc[mi][(nh) * 2 + j], 0, 0, 0);            \
      __builtin_amdgcn_s_setprio(0); }

    // prologue: tile 0, issue order = consumption order (Ah0,Ah1,Bh0,Bh1)
    STG_AH(0, 0, 0); STG_AH(0, 1, 0); STG_BH(0, 0, 0); STG_BH(0, 1, 0);

    int cur = 0;
    for (int t = 0; t < NT - 1; t++) {
        int k1 = (t + 1) * 64, nxt = cur ^ 1;
        // P1 (ks0,nh0): needs Ah0,Ah1,Bh0 of t -> vm(2) leaves Bh1(t)
        __builtin_amdgcn_s_waitcnt(WAITCNT_VM(2));
        __builtin_amdgcn_s_barrier();
        STG_AH(nxt, 0, k1);
        READ_A(cur, 0); READ_B2(cur, 0, 0);
        MMA2(0);
        // P2 (ks0,nh1): needs Bh1(t) -> vm(2) leaves Ah0(t+1)
        __builtin_amdgcn_s_waitcnt(WAITCNT_VM(2));
        __builtin_amdgcn_s_barrier();
        STG_AH(nxt, 1, k1);
        READ_B2(cur, 1, 0);
        MMA2(1);
        // P3 (ks1,nh0)
        __builtin_amdgcn_s_barrier();
        STG_BH(nxt, 0, k1);
        READ_A(cur, 1); READ_B2(cur, 0, 1);
        MMA2(0);
        // P4 (ks1,nh1)
        __builtin_amdgcn_s_barrier();
        STG_BH(nxt, 1, k1);
        READ_B2(cur, 1, 1);
        MMA2(1);
        cur = nxt;
    }
    // final K-tile
    __builtin_amdgcn_s_waitcnt(WAITCNT_VM(2));
    __builtin_amdgcn_s_barrier();
    READ_A(cur, 0); READ_B2(cur, 0, 0);
    MMA2(0);
    __builtin_amdgcn_s_waitcnt(WAITCNT_VM(0));
    READ_B2(cur, 1, 0);
    MMA2(1);
    READ_A(cur, 1); READ_B2(cur, 0, 1);
    MMA2(0);
    READ_B2(cur, 1, 1);
    MMA2(1);
#undef STG_AH
#undef STG_BH
#undef READ_A
#undef READ_B2
#undef MMA2

    // epilogue: +bias, optional gelu, masked store
    float bv[4];
#pragma unroll
    for (int ni = 0; ni < 4; ni++)
        bv[ni] = bias[(size_t)e * N + ct * 128 + (ni * 2 + wn) * 16 + m16];
#pragma unroll
    for (int mi = 0; mi < 4; mi++) {
#pragma unroll
        for (int rr = 0; rr < 4; rr++) {
            int row = (mi * 2 + wm) * 16 + quad * 4 + rr;
            if (m0 + row < cnt) {
                size_t orow = (size_t)(obase + m0 + row) * N + (size_t)ct * 128;
#pragma unroll
                for (int ni = 0; ni < 4; ni++) {
                    float v = acc[mi][ni][rr] + bv[ni];
                    if (GELU) v = gelu_exact(v);
                    Out[orow + (ni * 2 + wn) * 16 + m16] = (OutT)v;
                }
            }
        }
    }
}

// ---------------- Combine: out[t] = g0*y[s0] + g1*y[s1] ----------------
__launch_bounds__(256)
__global__ void combine_kernel(const float* __restrict__ ybuf,
                               const int* __restrict__ slot_of,
                               const float* __restrict__ topk_gate,
                               float* __restrict__ out) {
    int t = blockIdx.x;
    int tid = threadIdx.x;
    int s0 = slot_of[t * 2 + 0], s1 = slot_of[t * 2 + 1];
    float g0 = topk_gate[t * 2 + 0], g1 = topk_gate[t * 2 + 1];
    const float4* y0 = (const float4*)(ybuf + (size_t)s0 * DD);
    const float4* y1 = (const float4*)(ybuf + (size_t)s1 * DD);
    float4 a = y0[tid], b = y1[tid];
    float4 o;
    o.x = g0 * a.x + g1 * b.x;
    o.y = g0 * a.y + g1 * b.y;
    o.z = g0 * a.z + g1 * b.z;
    o.w = g0 * a.w + g1 * b.w;
    ((float4*)(out + (size_t)t * DD))[tid] = o;
}

extern "C" void kernel_launch(void* const* d_in, const int* in_sizes, int n_in,
                              void* d_out, int out_size, void* d_ws, size_t ws_size,
                              hipStream_t stream) {
    const float* x  = (const float*)d_in[0];
    const float* Wr = (const float*)d_in[1];
    const float* br = (const float*)d_in[2];
    const float* W1 = (const float*)d_in[3];
    const float* b1 = (const float*)d_in[4];
    const float* W2 = (const float*)d_in[5];
    const float* b2 = (const float*)d_in[6];
    float* out = (float*)d_out;

    char* ws = (char*)d_ws;
    int*    offsets    = (int*)(ws + WS_OFFSETS);
    int*    cursors    = (int*)(ws + WS_CURSORS);
    int*    topk_idx   = (int*)(ws + WS_TOPK_IDX);
    float*  topk_gate  = (float*)(ws + WS_TOPK_GATE);
    int*    slot_of    = (int*)(ws + WS_SLOT_OF);
    int*    token_list = (int*)(ws + WS_TOKEN_LIST);
    __bf16* xg         = (__bf16*)(ws + WS_XG);
    __bf16* hbuf       = (__bf16*)(ws + WS_HBUF);
    float*  ybuf       = (float*)(ws + WS_YBUF);
    __bf16* W1bt       = (__bf16*)(ws + WS_W1BT);
    __bf16* W2bt       = (__bf16*)(ws + WS_W2BT);
    int*    cntPart    = (int*)(ws + WS_CNT_PART);
    float*  impPart    = (float*)(ws + WS_IMP_PART);

    router_kernel<<<RBLK, 256, 0, stream>>>(x, Wr, br, cntPart, impPart, topk_idx, topk_gate);
    prefix_kernel<<<1, 64, 0, stream>>>(cntPart, impPart, offsets, cursors, out + (size_t)NTOK * DD);
    scatter_kernel<<<NTOK / 256, 256, 0, stream>>>(topk_idx, cursors, token_list, slot_of);
    gather_x_kernel<<<NSLOT, 256, 0, stream>>>(x, token_list, xg);

    // W1 [E][D=1024][H=4096] -> W1bt [E][H][D];  W2 [E][H=4096][D=1024] -> W2bt [E][D][H]
    transpose_w_kernel<<<dim3(HH / 64, DD / 64, EE), 256, 0, stream>>>(W1, W1bt, DD, HH);
    transpose_w_kernel<<<dim3(DD / 64, HH / 64, EE), 256, 0, stream>>>(W2, W2bt, HH, DD);

    // Stage 1: hbuf = gelu(xg @ W1 + b1)   [slots x 4096]; 256x256 tiles
    gemm256_kernel<HH, DD, true, __bf16>
        <<<dim3(HH / 256, 32, EE), 512, 0, stream>>>(xg, W1bt, b1, offsets, hbuf);
    // Stage 2: ybuf = hbuf @ W2 + b2       [slots x 1024]; 128x128 tiles
    gemm128d_kernel<DD, HH, false, float>
        <<<dim3(DD / 128, 64, EE), 256, 0, stream>>>(hbuf, W2bt, b2, offsets, ybuf);

    combine_kernel<<<NTOK, 256, 0, stream>>>(ybuf, slot_of, topk_gate, out);
}

// Round 4
// 622.983 us; speedup vs baseline: 1.2866x; 1.2866x over previous
//
#include <hip/hip_runtime.h>
#include <hip/hip_bf16.h>
#include <math.h>

// Problem constants (B=2,S=2048,D=1024,H=4096,E=8,K=2)
#define NTOK 4096
#define DD   1024
#define HH   4096
#define EE   8
#define NSLOT 8192          // NTOK * K (every token picks exactly 2 experts)
#define NSLOT_PAD 8448      // guard rows so a row tile never reads OOB
#define RBLK 128            // router blocks (32 tokens each)

typedef __bf16 bf16x8 __attribute__((ext_vector_type(8)));
typedef float  f32x4  __attribute__((ext_vector_type(4)));
typedef unsigned short u16x8 __attribute__((ext_vector_type(8)));

// s_waitcnt imm encoding (gfx9 family): vmcnt[3:0]+[15:14], expcnt[6:4], lgkmcnt[11:8]
#define WAITCNT_VM(n) (((n) & 0xF) | (0x7 << 4) | (0xF << 8) | (((n) >> 4) << 14))

// ---------------- ws layout (bytes) ----------------
#define WS_COUNTS     0
#define WS_CURSORS    64
#define WS_OFFSETS    128
#define WS_IMP        256
#define WS_TOPK_IDX   512
#define WS_TOPK_GATE  33280
#define WS_SLOT_OF    66048
#define WS_TOKEN_LIST 98816
// xg bf16 [8448][1024]         = 17,301,504 B
#define WS_XG         131584
// hbuf bf16 [8448][4096]       = 69,206,016 B  (rows >= 8192 are guard rows)
#define WS_HBUF       17433088
// ybuf f32 [8192][1024]        = 33,554,432 B
#define WS_YBUF       86639104
// W1bt bf16 [8][4096][1024]    = 67,108,864 B
#define WS_W1BT       120193536
// W2bt bf16 [8][1024][4096]    = 67,108,864 B
#define WS_W2BT       187302400
// total                        = 254,411,264 B (~242.6 MiB)
// Router partials live in hbuf's guard-row region (never stored by gemm1,
// read only as masked garbage by gemm2):
#define WS_CNT_PART   (WS_HBUF + (size_t)NSLOT * HH * 2)          // int[128*8]
#define WS_IMP_PART   (WS_HBUF + (size_t)NSLOT * HH * 2 + 4096)   // float[128*8]

__device__ __forceinline__ float gelu_exact(float v) {
    return 0.5f * v * (1.0f + erff(v * 0.70710678118654752f));
}

__device__ __forceinline__ void async_copy16(const __bf16* g, __bf16* l) {
    __builtin_amdgcn_global_load_lds(
        (const __attribute__((address_space(1))) void*)g,
        (__attribute__((address_space(3))) void*)l, 16, 0, 0);
}

// ---------------- Router: 8 lanes per token, no global atomics ----------
__launch_bounds__(256)
__global__ void router_kernel(const float* __restrict__ x,
                              const float* __restrict__ Wr,
                              const float* __restrict__ br,
                              int* __restrict__ cntPart,
                              float* __restrict__ impPart,
                              int* __restrict__ topk_idx,
                              float* __restrict__ topk_gate) {
    __shared__ float WrL[DD * EE];      // 32 KB
    __shared__ float impW[4][EE];
    __shared__ int cntL[EE];
    int tid = threadIdx.x;
    int lane = tid & 63, wave = tid >> 6;
    int grp = lane >> 3, e = lane & 7;
    int t = blockIdx.x * 32 + wave * 8 + grp;

    for (int i = tid; i < DD * EE / 4; i += 256)
        ((float4*)WrL)[i] = ((const float4*)Wr)[i];
    if (tid < EE) cntL[tid] = 0;
    __syncthreads();

    const float* xr = x + (size_t)t * DD;
    float acc = 0.f;
#pragma unroll 4
    for (int d = 0; d < DD; d += 4) {
        float4 xv = *(const float4*)(xr + d);
        acc = fmaf(xv.x, WrL[(d + 0) * EE + e], acc);
        acc = fmaf(xv.y, WrL[(d + 1) * EE + e], acc);
        acc = fmaf(xv.z, WrL[(d + 2) * EE + e], acc);
        acc = fmaf(xv.w, WrL[(d + 3) * EE + e], acc);
    }
    float l = acc + br[e];

    // softmax prob for (t,e) across the 8 lanes of this token
    float m = l;
#pragma unroll
    for (int mk = 1; mk <= 4; mk <<= 1) m = fmaxf(m, __shfl_xor(m, mk, 64));
    float p = expf(l - m);
    float s = p;
#pragma unroll
    for (int mk = 1; mk <= 4; mk <<= 1) s += __shfl_xor(s, mk, 64);
    p /= s;

    // top-1 argmax (ties -> lowest index, matching jax.lax.top_k)
    float bl = l; int be = e;
#pragma unroll
    for (int mk = 1; mk <= 4; mk <<= 1) {
        float ol = __shfl_xor(bl, mk, 64);
        int   oe = __shfl_xor(be, mk, 64);
        if (ol > bl || (ol == bl && oe < be)) { bl = ol; be = oe; }
    }
    int e1 = be; float l1 = bl;
    // top-2
    float cl = (e == e1) ? -INFINITY : l; int ce = e;
#pragma unroll
    for (int mk = 1; mk <= 4; mk <<= 1) {
        float ol = __shfl_xor(cl, mk, 64);
        int   oe = __shfl_xor(ce, mk, 64);
        if (ol > cl || (ol == cl && oe < ce)) { cl = ol; ce = oe; }
    }
    int e2 = ce; float l2 = cl;

    if (e == 0) {
        float bb = expf(l2 - l1);        // <= 1
        float g1 = 1.f / (1.f + bb);
        topk_idx[t * 2 + 0] = e1; topk_idx[t * 2 + 1] = e2;
        topk_gate[t * 2 + 0] = g1; topk_gate[t * 2 + 1] = bb * g1;
        atomicAdd(&cntL[e1], 1);         // LDS atomics only
        atomicAdd(&cntL[e2], 1);
    }

    // importance: sum p over the 8 token-groups in this wave
#pragma unroll
    for (int mk = 8; mk <= 32; mk <<= 1) p += __shfl_xor(p, mk, 64);
    if (lane < 8) impW[wave][lane] = p;
    __syncthreads();
    if (tid < EE) {
        float v = impW[0][tid] + impW[1][tid] + impW[2][tid] + impW[3][tid];
        impPart[blockIdx.x * EE + tid] = v;
        cntPart[blockIdx.x * EE + tid] = cntL[tid];
    }
}

// ---- Scatter (prefix-free): every block derives offsets deterministically --
// Each of the 16 blocks reads cntPart (128x8 ints), computes per-expert
// totals and the count from router-blocks preceding its own token range.
// Slot base = exclusive-scan(totals)[e] + before[e]; within-block rank via
// LDS atomics.  No global cursors, no init, no serial prefix kernel.
// Block 0 additionally publishes offsets[] and the aux loss.
__launch_bounds__(256)
__global__ void scatter_kernel(const int* __restrict__ topk_idx,
                               const int* __restrict__ cntPart,
                               const float* __restrict__ impPart,
                               int* __restrict__ offsets,
                               int* __restrict__ token_list,
                               int* __restrict__ slot_of,
                               float* __restrict__ aux_out) {
    __shared__ int tot[EE], bef[EE], lcnt[EE];
    __shared__ float impS[EE];
    __shared__ int off[EE + 1];
    int tid = threadIdx.x, b = blockIdx.x;
    if (tid < EE) { tot[tid] = 0; bef[tid] = 0; lcnt[tid] = 0; impS[tid] = 0.f; }
    __syncthreads();
    // 1024 (rb,e) entries, 4 per thread
#pragma unroll
    for (int i = 0; i < 4; i++) {
        int idx = tid * 4 + i;          // idx = rb*8 + e
        int rb = idx >> 3, e = idx & 7;
        int c = cntPart[idx];
        atomicAdd(&tot[e], c);
        if (rb < b * 8) atomicAdd(&bef[e], c);
        if (b == 0) atomicAdd(&impS[e], impPart[idx]);
    }
    __syncthreads();
    if (tid == 0) {
        int o = 0;
        for (int e = 0; e < EE; e++) { off[e] = o; o += tot[e]; }
        off[EE] = o;
        if (b == 0) {
            for (int e = 0; e <= EE; e++) offsets[e] = off[e];
            float aux = 0.f;
            for (int e = 0; e < EE; e++) {
                float d = impS[e] / (float)NTOK - 1.0f / (float)EE;
                aux += d * d;
            }
            aux_out[0] = aux / (float)EE;
        }
    }
    __syncthreads();
    int t = b * 256 + tid;
    int e0 = topk_idx[t * 2 + 0], e1 = topk_idx[t * 2 + 1];
    int r0 = atomicAdd(&lcnt[e0], 1);
    int r1 = atomicAdd(&lcnt[e1], 1);
    int s0 = off[e0] + bef[e0] + r0;
    int s1 = off[e1] + bef[e1] + r1;
    token_list[s0] = t; token_list[s1] = t;
    slot_of[t * 2 + 0] = s0; slot_of[t * 2 + 1] = s1;
}

// ---------------- Gather x rows into packed bf16 slot rows ----------------
__launch_bounds__(256)
__global__ void gather_x_kernel(const float* __restrict__ x,
                                const int* __restrict__ token_list,
                                __bf16* __restrict__ xg) {
    int s = blockIdx.x;
    int t = token_list[s];
    int tid = threadIdx.x;           // 256 threads x float4 = 1024 elems
    float4 v = ((const float4*)(x + (size_t)t * DD))[tid];
    __bf16 tmp[4] __attribute__((aligned(8)));
    tmp[0] = (__bf16)v.x; tmp[1] = (__bf16)v.y;
    tmp[2] = (__bf16)v.z; tmp[3] = (__bf16)v.w;
    ((ushort4*)(xg + (size_t)s * DD))[tid] = *(ushort4*)tmp;
}

// ------- Weight convert+transpose, both W1 and W2 in ONE launch ----------
// [E][R][C] f32 -> [E][C][R] bf16.  Flat 1D grid of 16384 blocks:
// id < 8192 -> W1 (R=1024,C=4096); else W2 (R=4096,C=1024).
__launch_bounds__(256)
__global__ void transpose_w2_kernel(const float* __restrict__ W1,
                                    const float* __restrict__ W2,
                                    __bf16* __restrict__ W1bt,
                                    __bf16* __restrict__ W2bt) {
    int id = blockIdx.x;
    bool isw2 = id >= 8192;
    int rem = id & 8191;
    int e = rem >> 10, t = rem & 1023;
    const float* in; __bf16* out; int R, C, cx, ry;
    if (!isw2) { in = W1; out = W1bt; R = DD; C = HH; cx = t & 63; ry = t >> 6; }
    else       { in = W2; out = W2bt; R = HH; C = DD; cx = t & 15; ry = t >> 4; }
    int c0 = cx * 64, r0 = ry * 64;
    __shared__ float tile[64][65];
    int tid = threadIdx.x;
    const float* ip = in + (size_t)e * R * C;
#pragma unroll
    for (int i = 0; i < 4; i++) {
        int flat = i * 256 + tid;
        int r = flat >> 4, c4 = (flat & 15) * 4;
        float4 v = *(const float4*)(ip + (size_t)(r0 + r) * C + c0 + c4);
        tile[r][c4 + 0] = v.x; tile[r][c4 + 1] = v.y;
        tile[r][c4 + 2] = v.z; tile[r][c4 + 3] = v.w;
    }
    __syncthreads();
    __bf16* op = out + (size_t)e * C * R;
    // write side: 16B per lane (ushort8), 2 passes
#pragma unroll
    for (int i = 0; i < 2; i++) {
        int flat = i * 256 + tid;
        int c = flat >> 3, r8 = (flat & 7) * 8;
        __bf16 tmp[8] __attribute__((aligned(16)));
#pragma unroll
        for (int j = 0; j < 8; j++) tmp[j] = (__bf16)tile[r8 + j][c];
        *(u16x8*)(op + (size_t)(c0 + c) * R + r0 + r8) = *(u16x8*)tmp;
    }
}

// ---------------- Grouped GEMM: 128x128 tile, BK=64, 2 blocks/CU ----------
// (round-2 proven config: 512 thr = 8 waves in 4Mx2N grid, wave tile 32x64;
// 64 KB LDS -> 2 blocks/CU; per K-tile 4 global_load_lds/thread; 2 phases
// with counted vmcnt (1 then 3), never drained mid-loop; setprio around
// each 8-MFMA cluster; XOR chunk swizzle, 0 bank conflicts measured.)
template <int N, int K, bool GELU, typename OutT>
__launch_bounds__(512, 4)
__global__ void gemm128_kernel(const __bf16* __restrict__ A,
                               const __bf16* __restrict__ Bt,
                               const float* __restrict__ bias,
                               const int* __restrict__ offsets,
                               OutT* __restrict__ Out) {
    constexpr int NT = K / 64;
    int e = blockIdx.z, ct = blockIdx.x, rt = blockIdx.y;
    int obase = offsets[e], cnt = offsets[e + 1] - obase;
    int m0 = rt * 128;
    if (m0 >= cnt) return;

    __shared__ __bf16 As[2][2][8 * 512];   // [dbuf][half: rows 0-63 / 64-127]
    __shared__ __bf16 Bs[2][16 * 512];     // [dbuf] 128 rows x 64 K

    int tid = threadIdx.x, lane = tid & 63, wave = tid >> 6;
    int quad = lane >> 4, m16 = lane & 15;
    int wm = wave & 3, wn = wave >> 2;     // 4 x 2 wave grid
    int srow = lane >> 3;                  // row within 8-row chunk
    int scol = ((lane & 7) ^ srow) * 8;    // swizzled bf16 col offset

    const __bf16* Ag = A + (size_t)(obase + m0) * K + scol;
    const __bf16* Bg = Bt + ((size_t)e * N + (size_t)ct * 128) * K + scol;

    // per-lane global src pointers
    const __bf16* pA[2];                   // A half h: rows h*64 + wave*8+srow
    const __bf16* pB[2];                   // B pass p: rows p*64 + wave*8+srow
#pragma unroll
    for (int h = 0; h < 2; h++) pA[h] = Ag + (size_t)(h * 64 + wave * 8 + srow) * K;
#pragma unroll
    for (int p = 0; p < 2; p++) pB[p] = Bg + (size_t)(p * 64 + wave * 8 + srow) * K;

    // fragment LDS read bases (element offsets); swz key = m16&7 for all frags
    int swz = m16 & 7;
    int abase = (wm * 2 + (m16 >> 3)) * 512 + swz * 64;          // local row wm*16+m16
    int bbase[4];
#pragma unroll
    for (int ni = 0; ni < 4; ni++)
        bbase[ni] = (ni * 4 + wn * 2 + (m16 >> 3)) * 512 + swz * 64;  // row (ni*2+wn)*16+m16

    f32x4 acc[2][4] = {};
    bf16x8 af[2], bfr[4][2];

#define STG_A(buf, h, k0) async_copy16(pA[h] + (k0), &As[buf][h][wave * 512]);
#define STG_B(buf, k0)                                                        \
    { async_copy16(pB[0] + (k0), &Bs[buf][wave * 512]);                       \
      async_copy16(pB[1] + (k0), &Bs[buf][(wave + 8) * 512]); }

#define READ_A(buf, h)                                                        \
    { af[0] = *(const bf16x8*)(&As[buf][h][abase] + ((quad ^ swz) * 8));      \
      af[1] = *(const bf16x8*)(&As[buf][h][abase] + (((4 + quad) ^ swz) * 8)); }
#define READ_B(buf)                                                           \
    { _Pragma("unroll")                                                       \
      for (int ni = 0; ni < 4; ni++) {                                        \
          bfr[ni][0] = *(const bf16x8*)(&Bs[buf][bbase[ni]] + ((quad ^ swz) * 8)); \
          bfr[ni][1] = *(const bf16x8*)(&Bs[buf][bbase[ni]] + (((4 + quad) ^ swz) * 8)); } }

#define MMA(h)                                                                \
    { __builtin_amdgcn_s_setprio(1);                                         \
      _Pragma("unroll")                                                       \
      for (int kk = 0; kk < 2; kk++)                                          \
          _Pragma("unroll")                                                   \
          for (int ni = 0; ni < 4; ni++)                                      \
              acc[h][ni] = __builtin_amdgcn_mfma_f32_16x16x32_bf16(           \
                  af[kk], bfr[ni][kk], acc[h][ni], 0, 0, 0);                  \
      __builtin_amdgcn_s_setprio(0); }

    // prologue: stage K-tile 0; issue order A0, B, B, A1 (P1 needs A0+B)
    STG_A(0, 0, 0);
    STG_B(0, 0);
    STG_A(0, 1, 0);

    int cur = 0;
    for (int t = 0; t < NT - 1; t++) {
        int k1 = (t + 1) * 64, nxt = cur ^ 1;
        // P1: needs A-h0(t) + B(t); leaves A-h1(t) in flight
        __builtin_amdgcn_s_waitcnt(WAITCNT_VM(1));
        __builtin_amdgcn_s_barrier();
        READ_A(cur, 0); READ_B(cur);
        STG_A(nxt, 0, k1); STG_B(nxt, k1);
        MMA(0);
        // P2: needs A-h1(t); leaves t+1's A0,B,B (3) in flight
        __builtin_amdgcn_s_waitcnt(WAITCNT_VM(3));
        __builtin_amdgcn_s_barrier();
        READ_A(cur, 1);
        STG_A(nxt, 1, k1);
        MMA(1);
        cur = nxt;
    }
    // last K-tile: no prefetch, draining waits
    __builtin_amdgcn_s_waitcnt(WAITCNT_VM(1));
    __builtin_amdgcn_s_barrier();
    READ_A(cur, 0); READ_B(cur);
    MMA(0);
    __builtin_amdgcn_s_waitcnt(WAITCNT_VM(0));
    __builtin_amdgcn_s_barrier();
    READ_A(cur, 1);
    MMA(1);
#undef STG_A
#undef STG_B
#undef READ_A
#undef READ_B
#undef MMA

    // epilogue: +bias, optional gelu, masked store
    float bv[4];
#pragma unroll
    for (int ni = 0; ni < 4; ni++)
        bv[ni] = bias[(size_t)e * N + ct * 128 + (ni * 2 + wn) * 16 + m16];
#pragma unroll
    for (int mi = 0; mi < 2; mi++) {
#pragma unroll
        for (int rr = 0; rr < 4; rr++) {
            int row = (mi * 4 + wm) * 16 + quad * 4 + rr;
            if (m0 + row < cnt) {
                size_t orow = (size_t)(obase + m0 + row) * N + (size_t)ct * 128;
#pragma unroll
                for (int ni = 0; ni < 4; ni++) {
                    float v = acc[mi][ni][rr] + bv[ni];
                    if (GELU) v = gelu_exact(v);
                    Out[orow + (ni * 2 + wn) * 16 + m16] = (OutT)v;
                }
            }
        }
    }
}

// ---------------- Combine: out[t] = g0*y[s0] + g1*y[s1] ----------------
__launch_bounds__(256)
__global__ void combine_kernel(const float* __restrict__ ybuf,
                               const int* __restrict__ slot_of,
                               const float* __restrict__ topk_gate,
                               float* __restrict__ out) {
    int t = blockIdx.x;
    int tid = threadIdx.x;
    int s0 = slot_of[t * 2 + 0], s1 = slot_of[t * 2 + 1];
    float g0 = topk_gate[t * 2 + 0], g1 = topk_gate[t * 2 + 1];
    const float4* y0 = (const float4*)(ybuf + (size_t)s0 * DD);
    const float4* y1 = (const float4*)(ybuf + (size_t)s1 * DD);
    float4 a = y0[tid], b = y1[tid];
    float4 o;
    o.x = g0 * a.x + g1 * b.x;
    o.y = g0 * a.y + g1 * b.y;
    o.z = g0 * a.z + g1 * b.z;
    o.w = g0 * a.w + g1 * b.w;
    ((float4*)(out + (size_t)t * DD))[tid] = o;
}

extern "C" void kernel_launch(void* const* d_in, const int* in_sizes, int n_in,
                              void* d_out, int out_size, void* d_ws, size_t ws_size,
                              hipStream_t stream) {
    const float* x  = (const float*)d_in[0];
    const float* Wr = (const float*)d_in[1];
    const float* br = (const float*)d_in[2];
    const float* W1 = (const float*)d_in[3];
    const float* b1 = (const float*)d_in[4];
    const float* W2 = (const float*)d_in[5];
    const float* b2 = (const float*)d_in[6];
    float* out = (float*)d_out;

    char* ws = (char*)d_ws;
    int*    offsets    = (int*)(ws + WS_OFFSETS);
    int*    topk_idx   = (int*)(ws + WS_TOPK_IDX);
    float*  topk_gate  = (float*)(ws + WS_TOPK_GATE);
    int*    slot_of    = (int*)(ws + WS_SLOT_OF);
    int*    token_list = (int*)(ws + WS_TOKEN_LIST);
    __bf16* xg         = (__bf16*)(ws + WS_XG);
    __bf16* hbuf       = (__bf16*)(ws + WS_HBUF);
    float*  ybuf       = (float*)(ws + WS_YBUF);
    __bf16* W1bt       = (__bf16*)(ws + WS_W1BT);
    __bf16* W2bt       = (__bf16*)(ws + WS_W2BT);
    int*    cntPart    = (int*)(ws + WS_CNT_PART);
    float*  impPart    = (float*)(ws + WS_IMP_PART);

    router_kernel<<<RBLK, 256, 0, stream>>>(x, Wr, br, cntPart, impPart, topk_idx, topk_gate);
    // scatter computes offsets + aux internally (prefix kernel removed)
    scatter_kernel<<<NTOK / 256, 256, 0, stream>>>(topk_idx, cntPart, impPart,
                                                   offsets, token_list, slot_of,
                                                   out + (size_t)NTOK * DD);
    gather_x_kernel<<<NSLOT, 256, 0, stream>>>(x, token_list, xg);

    // W1 [E][D][H] -> W1bt [E][H][D] and W2 [E][H][D] -> W2bt [E][D][H], one launch
    transpose_w2_kernel<<<16384, 256, 0, stream>>>(W1, W2, W1bt, W2bt);

    // rt=16 covers cnt<=2048/expert (balanced routing gives max ~1.3k; 1.6x margin)
    // Stage 1: hbuf = gelu(xg @ W1 + b1)   [slots x 4096]
    gemm128_kernel<HH, DD, true, __bf16>
        <<<dim3(HH / 128, 16, EE), 512, 0, stream>>>(xg, W1bt, b1, offsets, hbuf);
    // Stage 2: ybuf = hbuf @ W2 + b2       [slots x 1024]
    gemm128_kernel<DD, HH, false, float>
        <<<dim3(DD / 128, 16, EE), 512, 0, stream>>>(hbuf, W2bt, b2, offsets, ybuf);

    combine_kernel<<<NTOK, 256, 0, stream>>>(ybuf, slot_of, topk_gate, out);
}

// Round 5
// 610.683 us; speedup vs baseline: 1.3125x; 1.0201x over previous
//
#include <hip/hip_runtime.h>
#include <hip/hip_bf16.h>
#include <math.h>

// Problem constants (B=2,S=2048,D=1024,H=4096,E=8,K=2)
#define NTOK 4096
#define DD   1024
#define HH   4096
#define EE   8
#define NSLOT 8192          // NTOK * K (every token picks exactly 2 experts)
#define NSLOT_PAD 8448      // guard rows so a row tile never reads OOB
#define RBLK 1024           // router blocks (4 tokens each, 1 wave/token)

typedef __bf16 bf16x8 __attribute__((ext_vector_type(8)));
typedef float  f32x4  __attribute__((ext_vector_type(4)));
typedef unsigned short u16x8 __attribute__((ext_vector_type(8)));

// ---------------- ws layout (bytes) ----------------
#define WS_COUNTS     0
#define WS_CURSORS    64
#define WS_OFFSETS    128
#define WS_IMP        256
#define WS_TOPK_IDX   512
#define WS_TOPK_GATE  33280
#define WS_SLOT_OF    66048
#define WS_TOKEN_LIST 98816
// xg bf16 [8448][1024]         = 17,301,504 B
#define WS_XG         131584
// hbuf bf16 [8448][4096]       = 69,206,016 B  (rows >= 8192 are guard rows)
#define WS_HBUF       17433088
// ybuf f32 [8192][1024]        = 33,554,432 B
#define WS_YBUF       86639104
// W1bt bf16 [8][4096][1024]    = 67,108,864 B
#define WS_W1BT       120193536
// W2bt bf16 [8][1024][4096]    = 67,108,864 B
#define WS_W2BT       187302400
// total                        = 254,411,264 B (~242.6 MiB)
// Router partials live in hbuf's guard-row region (never stored by gemm1,
// read only as masked garbage by gemm2): int[1024*8] + float[1024*8]
#define WS_CNT_PART   (WS_HBUF + (size_t)NSLOT * HH * 2)
#define WS_IMP_PART   (WS_HBUF + (size_t)NSLOT * HH * 2 + 32768)

__device__ __forceinline__ float gelu_exact(float v) {
    return 0.5f * v * (1.0f + erff(v * 0.70710678118654752f));
}

__device__ __forceinline__ void async_copy16(const __bf16* g, __bf16* l) {
    __builtin_amdgcn_global_load_lds(
        (const __attribute__((address_space(1))) void*)g,
        (__attribute__((address_space(3))) void*)l, 16, 0, 0);
}

// ---------------- Router: one wave per token, Wr straight from L2 --------
// 1024 blocks x 256 thr (4 waves = 4 tokens).  Lane owns dims
// d = lane*16..lane*16+15: loads 4 float4 of x and 32 float4 of Wr (512 B
// contiguous per lane -> fully coalesced, L2-hot).  8 accumulators reduced
// across the wave by butterfly shfl; every lane then holds all 8 logits and
// computes softmax/top2 redundantly (uniform, no divergence).
__launch_bounds__(256)
__global__ void router_kernel(const float* __restrict__ x,
                              const float* __restrict__ Wr,
                              const float* __restrict__ br,
                              int* __restrict__ cntPart,
                              float* __restrict__ impPart,
                              int* __restrict__ topk_idx,
                              float* __restrict__ topk_gate) {
    __shared__ int cntL[EE];
    __shared__ float impL[EE];
    int tid = threadIdx.x;
    int lane = tid & 63, wave = tid >> 6;
    int t = blockIdx.x * 4 + wave;

    if (tid < EE) { cntL[tid] = 0; impL[tid] = 0.f; }
    __syncthreads();

    // x slice: 16 dims per lane
    const float4* xp = (const float4*)(x + (size_t)t * DD + lane * 16);
    float xs[16] __attribute__((aligned(16)));
    *(float4*)&xs[0]  = xp[0];
    *(float4*)&xs[4]  = xp[1];
    *(float4*)&xs[8]  = xp[2];
    *(float4*)&xs[12] = xp[3];

    // Wr rows d0..d0+15, 8 cols each: 512 B contiguous per lane
    const float4* wp = (const float4*)(Wr + (size_t)lane * 16 * EE);
    float a[8] = {0.f, 0.f, 0.f, 0.f, 0.f, 0.f, 0.f, 0.f};
#pragma unroll
    for (int j = 0; j < 16; j++) {
        float4 w0 = wp[j * 2 + 0];
        float4 w1 = wp[j * 2 + 1];
        float xj = xs[j];
        a[0] = fmaf(xj, w0.x, a[0]); a[1] = fmaf(xj, w0.y, a[1]);
        a[2] = fmaf(xj, w0.z, a[2]); a[3] = fmaf(xj, w0.w, a[3]);
        a[4] = fmaf(xj, w1.x, a[4]); a[5] = fmaf(xj, w1.y, a[5]);
        a[6] = fmaf(xj, w1.z, a[6]); a[7] = fmaf(xj, w1.w, a[7]);
    }
    // butterfly reduce over 64 lanes -> every lane holds full sums
#pragma unroll
    for (int e = 0; e < 8; e++)
#pragma unroll
        for (int mk = 1; mk < 64; mk <<= 1)
            a[e] += __shfl_xor(a[e], mk, 64);

    float l[8];
#pragma unroll
    for (int e = 0; e < 8; e++) l[e] = a[e] + br[e];

    // softmax probs (for importance)
    float m = l[0];
#pragma unroll
    for (int e = 1; e < 8; e++) m = fmaxf(m, l[e]);
    float p[8], s = 0.f;
#pragma unroll
    for (int e = 0; e < 8; e++) { p[e] = expf(l[e] - m); s += p[e]; }
    float inv = 1.f / s;

    // top-2 (ties -> lowest index, matching jax.lax.top_k)
    int e1 = 0; float l1 = l[0];
#pragma unroll
    for (int e = 1; e < 8; e++) if (l[e] > l1) { l1 = l[e]; e1 = e; }
    int e2 = -1; float l2 = -INFINITY;
#pragma unroll
    for (int e = 0; e < 8; e++)
        if (e != e1 && l[e] > l2) { l2 = l[e]; e2 = e; }

    if (lane == 0) {
        float bb = expf(l2 - l1);        // <= 1
        float g1 = 1.f / (1.f + bb);
        topk_idx[t * 2 + 0] = e1; topk_idx[t * 2 + 1] = e2;
        topk_gate[t * 2 + 0] = g1; topk_gate[t * 2 + 1] = bb * g1;
        atomicAdd(&cntL[e1], 1);
        atomicAdd(&cntL[e2], 1);
#pragma unroll
        for (int e = 0; e < 8; e++) atomicAdd(&impL[e], p[e] * inv);
    }
    __syncthreads();
    if (tid < EE) {
        cntPart[blockIdx.x * EE + tid] = cntL[tid];
        impPart[blockIdx.x * EE + tid] = impL[tid];
    }
}

// ---- Scatter (prefix-free): register partials + shfl reduce ---------------
// 16 blocks x 256 thr.  Each thread sums 4 rows of cntPart[1024][8] into
// register tot/bef partials (bef = router blocks before this scatter block's
// token range), butterfly-reduces within the wave, cross-wave via LDS.
// Block 0 publishes offsets[] and the aux loss.
__launch_bounds__(256)
__global__ void scatter_kernel(const int* __restrict__ topk_idx,
                               const int* __restrict__ cntPart,
                               const float* __restrict__ impPart,
                               int* __restrict__ offsets,
                               int* __restrict__ token_list,
                               int* __restrict__ slot_of,
                               float* __restrict__ aux_out) {
    __shared__ int totW[4][EE], befW[4][EE];
    __shared__ float impW[4][EE];
    __shared__ int totS[EE], befS[EE], lcnt[EE];
    __shared__ int off[EE + 1];
    int tid = threadIdx.x, b = blockIdx.x;
    int lane = tid & 63, wave = tid >> 6;

    int myTot[8] = {0,0,0,0,0,0,0,0};
    int myBef[8] = {0,0,0,0,0,0,0,0};
    float myImp[8] = {0.f,0.f,0.f,0.f,0.f,0.f,0.f,0.f};
#pragma unroll
    for (int i = 0; i < 4; i++) {
        int rb = tid * 4 + i;
        const int* row = cntPart + rb * 8;
        const float* ir = impPart + rb * 8;
        bool isbef = rb < b * 64;
#pragma unroll
        for (int e = 0; e < 8; e++) {
            int c = row[e];
            myTot[e] += c;
            if (isbef) myBef[e] += c;
            myImp[e] += ir[e];
        }
    }
#pragma unroll
    for (int e = 0; e < 8; e++)
#pragma unroll
        for (int mk = 1; mk < 64; mk <<= 1) {
            myTot[e] += __shfl_xor(myTot[e], mk, 64);
            myBef[e] += __shfl_xor(myBef[e], mk, 64);
            myImp[e] += __shfl_xor(myImp[e], mk, 64);
        }
    if (lane == 0) {
#pragma unroll
        for (int e = 0; e < 8; e++) {
            totW[wave][e] = myTot[e];
            befW[wave][e] = myBef[e];
            impW[wave][e] = myImp[e];
        }
    }
    __syncthreads();
    if (tid < EE) {
        totS[tid] = totW[0][tid] + totW[1][tid] + totW[2][tid] + totW[3][tid];
        befS[tid] = befW[0][tid] + befW[1][tid] + befW[2][tid] + befW[3][tid];
        lcnt[tid] = 0;
    }
    __syncthreads();
    if (tid == 0) {
        int o = 0;
        for (int e = 0; e < EE; e++) { off[e] = o; o += totS[e]; }
        off[EE] = o;
        if (b == 0) {
            for (int e = 0; e <= EE; e++) offsets[e] = off[e];
            float aux = 0.f;
            for (int e = 0; e < EE; e++) {
                float im = impW[0][e] + impW[1][e] + impW[2][e] + impW[3][e];
                float d = im / (float)NTOK - 1.0f / (float)EE;
                aux += d * d;
            }
            aux_out[0] = aux / (float)EE;
        }
    }
    __syncthreads();
    int t = b * 256 + tid;
    int e0 = topk_idx[t * 2 + 0], e1 = topk_idx[t * 2 + 1];
    int r0 = atomicAdd(&lcnt[e0], 1);
    int r1 = atomicAdd(&lcnt[e1], 1);
    int s0 = off[e0] + befS[e0] + r0;
    int s1 = off[e1] + befS[e1] + r1;
    token_list[s0] = t; token_list[s1] = t;
    slot_of[t * 2 + 0] = s0; slot_of[t * 2 + 1] = s1;
}

// ---------------- Gather x rows into packed bf16 slot rows ----------------
__launch_bounds__(256)
__global__ void gather_x_kernel(const float* __restrict__ x,
                                const int* __restrict__ token_list,
                                __bf16* __restrict__ xg) {
    int s = blockIdx.x;
    int t = token_list[s];
    int tid = threadIdx.x;           // 256 threads x float4 = 1024 elems
    float4 v = ((const float4*)(x + (size_t)t * DD))[tid];
    __bf16 tmp[4] __attribute__((aligned(8)));
    tmp[0] = (__bf16)v.x; tmp[1] = (__bf16)v.y;
    tmp[2] = (__bf16)v.z; tmp[3] = (__bf16)v.w;
    ((ushort4*)(xg + (size_t)s * DD))[tid] = *(ushort4*)tmp;
}

// ------- Weight convert+transpose, both W1 and W2 in ONE launch ----------
// [E][R][C] f32 -> [E][C][R] bf16.  Flat 1D grid of 16384 blocks:
// id < 8192 -> W1 (R=1024,C=4096); else W2 (R=4096,C=1024).
__launch_bounds__(256)
__global__ void transpose_w2_kernel(const float* __restrict__ W1,
                                    const float* __restrict__ W2,
                                    __bf16* __restrict__ W1bt,
                                    __bf16* __restrict__ W2bt) {
    int id = blockIdx.x;
    bool isw2 = id >= 8192;
    int rem = id & 8191;
    int e = rem >> 10, t = rem & 1023;
    const float* in; __bf16* out; int R, C, cx, ry;
    if (!isw2) { in = W1; out = W1bt; R = DD; C = HH; cx = t & 63; ry = t >> 6; }
    else       { in = W2; out = W2bt; R = HH; C = DD; cx = t & 15; ry = t >> 4; }
    int c0 = cx * 64, r0 = ry * 64;
    __shared__ float tile[64][65];
    int tid = threadIdx.x;
    const float* ip = in + (size_t)e * R * C;
#pragma unroll
    for (int i = 0; i < 4; i++) {
        int flat = i * 256 + tid;
        int r = flat >> 4, c4 = (flat & 15) * 4;
        float4 v = *(const float4*)(ip + (size_t)(r0 + r) * C + c0 + c4);
        tile[r][c4 + 0] = v.x; tile[r][c4 + 1] = v.y;
        tile[r][c4 + 2] = v.z; tile[r][c4 + 3] = v.w;
    }
    __syncthreads();
    __bf16* op = out + (size_t)e * C * R;
    // write side: 16B per lane (ushort8), 2 passes
#pragma unroll
    for (int i = 0; i < 2; i++) {
        int flat = i * 256 + tid;
        int c = flat >> 3, r8 = (flat & 7) * 8;
        __bf16 tmp[8] __attribute__((aligned(16)));
#pragma unroll
        for (int j = 0; j < 8; j++) tmp[j] = (__bf16)tile[r8 + j][c];
        *(u16x8*)(op + (size_t)(c0 + c) * R + r0 + r8) = *(u16x8*)tmp;
    }
}

// ============ Grouped GEMM 1: m97 structure (TLP, single buffer) ==========
// 128x128 tile, BK=64, 256 thr = 4 waves 2x2 (wave tile 64x64 -> 32 MFMA
// per barrier pair).  Single 32 KB LDS buffer + full-drain loop
// {sync; stage; sync(compiler emits vmcnt0); compute} -- latency hidden by
// 4 blocks/CU (launch_bounds(256,4), VGPR<=128, LDS 32KB*4=128<=160).
// XOR chunk swizzle (0 bank conflicts measured): stage lane writes global
// col-chunk (lane&7)^(lane>>3); fragment reads chunk slot^(row&7).
template <int N, int K, bool GELU, typename OutT>
__launch_bounds__(256, 4)
__global__ void gemm97_kernel(const __bf16* __restrict__ A,
                              const __bf16* __restrict__ Bt,
                              const float* __restrict__ bias,
                              const int* __restrict__ offsets,
                              OutT* __restrict__ Out) {
    constexpr int NT = K / 64;
    int e = blockIdx.z, ct = blockIdx.x, rt = blockIdx.y;
    int obase = offsets[e], cnt = offsets[e + 1] - obase;
    int m0 = rt * 128;
    if (m0 >= cnt) return;

    __shared__ __bf16 As[16 * 512];      // 128 rows x 64 K (16 KB)
    __shared__ __bf16 Bs[16 * 512];

    int tid = threadIdx.x, lane = tid & 63, wave = tid >> 6;
    int quad = lane >> 4, m16 = lane & 15;
    int wm = wave & 1, wn = wave >> 1;   // 2x2 wave grid, wave tile 64x64
    int srow = lane >> 3;
    int scol = ((lane & 7) ^ srow) * 8;

    const __bf16* Ag = A + (size_t)(obase + m0) * K + scol;
    const __bf16* Bg = Bt + ((size_t)e * N + (size_t)ct * 128) * K + scol;
    const __bf16* pA[4];
    const __bf16* pB[4];
#pragma unroll
    for (int r = 0; r < 4; r++) {
        pA[r] = Ag + (size_t)((r * 4 + wave) * 8 + srow) * K;
        pB[r] = Bg + (size_t)((r * 4 + wave) * 8 + srow) * K;
    }

    f32x4 acc[4][4] = {};

    for (int kt = 0; kt < NT; kt++) {
        int k0 = kt * 64;
        __syncthreads();                 // all reads of LDS from prev iter done
#pragma unroll
        for (int r = 0; r < 4; r++)
            async_copy16(pA[r] + k0, &As[(r * 4 + wave) * 512]);
#pragma unroll
        for (int r = 0; r < 4; r++)
            async_copy16(pB[r] + k0, &Bs[(r * 4 + wave) * 512]);
        __syncthreads();                 // compiler drains vmcnt before barrier
        __builtin_amdgcn_s_setprio(1);
#pragma unroll
        for (int ks = 0; ks < 2; ks++) {
            bf16x8 af[4], bf[4];
#pragma unroll
            for (int mi = 0; mi < 4; mi++) {
                int r = wm * 64 + mi * 16 + m16;
                af[mi] = *(const bf16x8*)(&As[(r >> 3) * 512 + (r & 7) * 64
                                          + (((ks * 4 + quad) ^ (r & 7)) * 8)]);
            }
#pragma unroll
            for (int ni = 0; ni < 4; ni++) {
                int r = wn * 64 + ni * 16 + m16;
                bf[ni] = *(const bf16x8*)(&Bs[(r >> 3) * 512 + (r & 7) * 64
                                          + (((ks * 4 + quad) ^ (r & 7)) * 8)]);
            }
#pragma unroll
            for (int mi = 0; mi < 4; mi++)
#pragma unroll
                for (int ni = 0; ni < 4; ni++)
                    acc[mi][ni] = __builtin_amdgcn_mfma_f32_16x16x32_bf16(
                        af[mi], bf[ni], acc[mi][ni], 0, 0, 0);
        }
        __builtin_amdgcn_s_setprio(0);
    }

    // epilogue: +bias, optional gelu, masked store
    float bv[4];
#pragma unroll
    for (int ni = 0; ni < 4; ni++)
        bv[ni] = bias[(size_t)e * N + ct * 128 + wn * 64 + ni * 16 + m16];
#pragma unroll
    for (int mi = 0; mi < 4; mi++) {
#pragma unroll
        for (int rr = 0; rr < 4; rr++) {
            int row = wm * 64 + mi * 16 + quad * 4 + rr;
            if (m0 + row < cnt) {
                size_t orow = (size_t)(obase + m0 + row) * N
                              + (size_t)ct * 128 + wn * 64;
#pragma unroll
                for (int ni = 0; ni < 4; ni++) {
                    float v = acc[mi][ni][rr] + bv[ni];
                    if (GELU) v = gelu_exact(v);
                    Out[orow + ni * 16 + m16] = (OutT)v;
                }
            }
        }
    }
}

// ============ Grouped GEMM 2: same structure, 64x128 tile =================
// N=1024 output needs more blocks for a full 4/CU round: 64-row tiles give
// 8ct x ~16 active rt x 8e ~= 1024 active blocks.  4 waves 1Mx4N (wave tile
// 64x32), LDS 24 KB (A 8 KB + B 16 KB), full-drain loop as gemm97.
template <int N, int K, bool GELU, typename OutT>
__launch_bounds__(256, 4)
__global__ void gemm64_kernel(const __bf16* __restrict__ A,
                              const __bf16* __restrict__ Bt,
                              const float* __restrict__ bias,
                              const int* __restrict__ offsets,
                              OutT* __restrict__ Out) {
    constexpr int NT = K / 64;
    int e = blockIdx.z, ct = blockIdx.x, rt = blockIdx.y;
    int obase = offsets[e], cnt = offsets[e + 1] - obase;
    int m0 = rt * 64;
    if (m0 >= cnt) return;

    __shared__ __bf16 As[8 * 512];       // 64 rows x 64 K (8 KB)
    __shared__ __bf16 Bs[16 * 512];      // 128 rows x 64 K (16 KB)

    int tid = threadIdx.x, lane = tid & 63, wave = tid >> 6;
    int quad = lane >> 4, m16 = lane & 15;
    int wn = wave;                        // 1M x 4N, wave tile 64x32
    int srow = lane >> 3;
    int scol = ((lane & 7) ^ srow) * 8;

    const __bf16* Ag = A + (size_t)(obase + m0) * K + scol;
    const __bf16* Bg = Bt + ((size_t)e * N + (size_t)ct * 128) * K + scol;
    const __bf16* pA[2];
    const __bf16* pB[4];
#pragma unroll
    for (int r = 0; r < 2; r++)
        pA[r] = Ag + (size_t)((r * 4 + wave) * 8 + srow) * K;
#pragma unroll
    for (int r = 0; r < 4; r++)
        pB[r] = Bg + (size_t)((r * 4 + wave) * 8 + srow) * K;

    f32x4 acc[4][2] = {};

    for (int kt = 0; kt < NT; kt++) {
        int k0 = kt * 64;
        __syncthreads();
#pragma unroll
        for (int r = 0; r < 2; r++)
            async_copy16(pA[r] + k0, &As[(r * 4 + wave) * 512]);
#pragma unroll
        for (int r = 0; r < 4; r++)
            async_copy16(pB[r] + k0, &Bs[(r * 4 + wave) * 512]);
        __syncthreads();
        __builtin_amdgcn_s_setprio(1);
#pragma unroll
        for (int ks = 0; ks < 2; ks++) {
            bf16x8 af[4], bf[2];
#pragma unroll
            for (int mi = 0; mi < 4; mi++) {
                int r = mi * 16 + m16;
                af[mi] = *(const bf16x8*)(&As[(r >> 3) * 512 + (r & 7) * 64
                                          + (((ks * 4 + quad) ^ (r & 7)) * 8)]);
            }
#pragma unroll
            for (int ni = 0; ni < 2; ni++) {
                int r = wn * 32 + ni * 16 + m16;
                bf[ni] = *(const bf16x8*)(&Bs[(r >> 3) * 512 + (r & 7) * 64
                                          + (((ks * 4 + quad) ^ (r & 7)) * 8)]);
            }
#pragma unroll
            for (int mi = 0; mi < 4; mi++)
#pragma unroll
                for (int ni = 0; ni < 2; ni++)
                    acc[mi][ni] = __builtin_amdgcn_mfma_f32_16x16x32_bf16(
                        af[mi], bf[ni], acc[mi][ni], 0, 0, 0);
        }
        __builtin_amdgcn_s_setprio(0);
    }

    // epilogue: +bias, optional gelu, masked store
    float bv[2];
#pragma unroll
    for (int ni = 0; ni < 2; ni++)
        bv[ni] = bias[(size_t)e * N + ct * 128 + wn * 32 + ni * 16 + m16];
#pragma unroll
    for (int mi = 0; mi < 4; mi++) {
#pragma unroll
        for (int rr = 0; rr < 4; rr++) {
            int row = mi * 16 + quad * 4 + rr;
            if (m0 + row < cnt) {
                size_t orow = (size_t)(obase + m0 + row) * N
                              + (size_t)ct * 128 + wn * 32;
#pragma unroll
                for (int ni = 0; ni < 2; ni++) {
                    float v = acc[mi][ni][rr] + bv[ni];
                    if (GELU) v = gelu_exact(v);
                    Out[orow + ni * 16 + m16] = (OutT)v;
                }
            }
        }
    }
}

// ---------------- Combine: out[t] = g0*y[s0] + g1*y[s1] ----------------
__launch_bounds__(256)
__global__ void combine_kernel(const float* __restrict__ ybuf,
                               const int* __restrict__ slot_of,
                               const float* __restrict__ topk_gate,
                               float* __restrict__ out) {
    int t = blockIdx.x;
    int tid = threadIdx.x;
    int s0 = slot_of[t * 2 + 0], s1 = slot_of[t * 2 + 1];
    float g0 = topk_gate[t * 2 + 0], g1 = topk_gate[t * 2 + 1];
    const float4* y0 = (const float4*)(ybuf + (size_t)s0 * DD);
    const float4* y1 = (const float4*)(ybuf + (size_t)s1 * DD);
    float4 a = y0[tid], b = y1[tid];
    float4 o;
    o.x = g0 * a.x + g1 * b.x;
    o.y = g0 * a.y + g1 * b.y;
    o.z = g0 * a.z + g1 * b.z;
    o.w = g0 * a.w + g1 * b.w;
    ((float4*)(out + (size_t)t * DD))[tid] = o;
}

extern "C" void kernel_launch(void* const* d_in, const int* in_sizes, int n_in,
                              void* d_out, int out_size, void* d_ws, size_t ws_size,
                              hipStream_t stream) {
    const float* x  = (const float*)d_in[0];
    const float* Wr = (const float*)d_in[1];
    const float* br = (const float*)d_in[2];
    const float* W1 = (const float*)d_in[3];
    const float* b1 = (const float*)d_in[4];
    const float* W2 = (const float*)d_in[5];
    const float* b2 = (const float*)d_in[6];
    float* out = (float*)d_out;

    char* ws = (char*)d_ws;
    int*    offsets    = (int*)(ws + WS_OFFSETS);
    int*    topk_idx   = (int*)(ws + WS_TOPK_IDX);
    float*  topk_gate  = (float*)(ws + WS_TOPK_GATE);
    int*    slot_of    = (int*)(ws + WS_SLOT_OF);
    int*    token_list = (int*)(ws + WS_TOKEN_LIST);
    __bf16* xg         = (__bf16*)(ws + WS_XG);
    __bf16* hbuf       = (__bf16*)(ws + WS_HBUF);
    float*  ybuf       = (float*)(ws + WS_YBUF);
    __bf16* W1bt       = (__bf16*)(ws + WS_W1BT);
    __bf16* W2bt       = (__bf16*)(ws + WS_W2BT);
    int*    cntPart    = (int*)(ws + WS_CNT_PART);
    float*  impPart    = (float*)(ws + WS_IMP_PART);

    router_kernel<<<RBLK, 256, 0, stream>>>(x, Wr, br, cntPart, impPart, topk_idx, topk_gate);
    scatter_kernel<<<NTOK / 256, 256, 0, stream>>>(topk_idx, cntPart, impPart,
                                                   offsets, token_list, slot_of,
                                                   out + (size_t)NTOK * DD);
    gather_x_kernel<<<NSLOT, 256, 0, stream>>>(x, token_list, xg);

    // W1 [E][D][H] -> W1bt [E][H][D] and W2 [E][H][D] -> W2bt [E][D][H], one launch
    transpose_w2_kernel<<<16384, 256, 0, stream>>>(W1, W2, W1bt, W2bt);

    // Stage 1: hbuf = gelu(xg @ W1 + b1)   [slots x 4096]; 128x128 tiles
    gemm97_kernel<HH, DD, true, __bf16>
        <<<dim3(HH / 128, 16, EE), 256, 0, stream>>>(xg, W1bt, b1, offsets, hbuf);
    // Stage 2: ybuf = hbuf @ W2 + b2       [slots x 1024]; 64x128 tiles
    gemm64_kernel<DD, HH, false, float>
        <<<dim3(DD / 128, 32, EE), 256, 0, stream>>>(hbuf, W2bt, b2, offsets, ybuf);

    combine_kernel<<<NTOK, 256, 0, stream>>>(ybuf, slot_of, topk_gate, out);
}